// Round 7
// baseline (294.733 us; speedup 1.0000x reference)
//
#include <hip/hip_runtime.h>
#include <hip/hip_bf16.h>

typedef short short8 __attribute__((ext_vector_type(8)));
typedef float floatx4 __attribute__((ext_vector_type(4)));

#define NGROUP 512
#define RREG 256
#define D 512
#define ROWS 131072
#define FBAR_ELEMS (NGROUP * D)   // 262144

__device__ __forceinline__ unsigned short f2bf(float f) {
    unsigned int u = __float_as_uint(f);
    unsigned int r = (u + 0x7fffu + ((u >> 16) & 1u)) >> 16;
    return (unsigned short)r;
}
__device__ __forceinline__ float fast_tanh(float x) {
    float cx = fminf(fmaxf(x, -9.5f), 9.5f);
    float e  = __builtin_amdgcn_exp2f(cx * 2.8853900817779268f);  // e^{2cx}
    return (e - 1.f) * __builtin_amdgcn_rcpf(e + 1.f);
}

// ---- kernel 1: W1 fp32 -> bf16, plain row-major [outcol][k] ----
__global__ __launch_bounds__(256) void conv_w1(const float* __restrict__ W1,
                                               unsigned short* __restrict__ W1bf) {
    int i = (blockIdx.x * 256 + threadIdx.x) * 4;
    float4 v = *reinterpret_cast<const float4*>(W1 + i);
    ushort4 o;
    o.x = f2bf(v.x); o.y = f2bf(v.y); o.z = f2bf(v.z); o.w = f2bf(v.w);
    *reinterpret_cast<ushort4*>(W1bf + i) = o;
}

// ---- kernel 2: score GEMM ----
// 4096 blocks x 512 threads (8 waves). Block = 32 rows of x -> 32 KB LDS
// -> 4 blocks/CU for latency hiding (R5/R6 lesson: this kernel is
// latency-bound; concurrency, not manual pipelining, is the lever).
// LDS swizzle byte ^= (row&15)<<6: A-frag reads are provably
// conflict-free (64 lanes -> 64 distinct 16B slots), fixing R5's 4.2M
// bank-conflict cycles. Wave w computes the 32-row x 64-col slice
// cols [w*64,w*64+64): A from LDS, B from global (L2-resident W1bf).
__global__ __launch_bounds__(512) void score_gemm(
    const float* __restrict__ x, const unsigned short* __restrict__ W1bf,
    const float* __restrict__ b1, const float* __restrict__ W2v,
    float* __restrict__ inv_norm, float* __restrict__ scores) {

    __shared__ unsigned short A_lds[32 * 512];   // 32 KiB, swizzled
    __shared__ float inv_s[32];
    __shared__ float scorebuf[8][32];            // 1 KiB

    const int t = threadIdx.x;
    const int lane = t & 63;
    const int w = t >> 6;          // wave 0..7
    const int cl = lane & 15;
    const int hi = lane >> 4;
    const size_t row0 = (size_t)blockIdx.x * 32;

    // ---- stage A: wave w owns rows w*4..w*4+3; loads issued first (MLP) ----
    {
        const float* xw = x + (row0 + w * 4) * (size_t)D;
        float4 v[4][2];
        #pragma unroll
        for (int i = 0; i < 4; ++i) {      // 8 coalesced 1KB-segment loads in flight
            v[i][0] = *reinterpret_cast<const float4*>(xw + (size_t)i * D + lane * 4);
            v[i][1] = *reinterpret_cast<const float4*>(xw + (size_t)i * D + 256 + lane * 4);
        }
        #pragma unroll
        for (int i = 0; i < 4; ++i) {
            int r = w * 4 + i;
            float4 p = v[i][0], q = v[i][1];
            float ss = p.x*p.x + p.y*p.y + p.z*p.z + p.w*p.w
                     + q.x*q.x + q.y*q.y + q.z*q.z + q.w*q.w;
            #pragma unroll
            for (int m = 1; m < 64; m <<= 1) ss += __shfl_xor(ss, m, 64);
            float inv = 1.0f / fmaxf(sqrtf(ss), 1e-12f);
            if (lane == 0) { inv_s[r] = inv; inv_norm[row0 + r] = inv; }
            ushort4 p0, p1;
            p0.x = f2bf(p.x); p0.y = f2bf(p.y); p0.z = f2bf(p.z); p0.w = f2bf(p.w);
            p1.x = f2bf(q.x); p1.y = f2bf(q.y); p1.z = f2bf(q.z); p1.w = f2bf(q.w);
            const int m16 = (r & 15) << 6;   // conflict-free swizzle mask
            *reinterpret_cast<ushort4*>(
                (char*)A_lds + r * 1024 + ((lane * 8) ^ m16)) = p0;
            *reinterpret_cast<ushort4*>(
                (char*)A_lds + r * 1024 + ((512 + lane * 8) ^ m16)) = p1;
        }
    }
    __syncthreads();

    // ---- GEMM: K=512 in 16 steps of 32; compiler-scheduled (R6 lesson) ----
    floatx4 acc[2][4];
    #pragma unroll
    for (int tt = 0; tt < 2; ++tt)
        #pragma unroll
        for (int f = 0; f < 4; ++f) acc[tt][f] = floatx4{0, 0, 0, 0};

    const unsigned short* Bbase = W1bf + ((size_t)(w * 64) << 9);  // cols w*64..
    const int aswz = (cl & 15) << 6;

    #pragma unroll 4
    for (int ks = 0; ks < 16; ++ks) {
        short8 bfr[4], afr[2];
        #pragma unroll
        for (int f = 0; f < 4; ++f)
            bfr[f] = *reinterpret_cast<const short8*>(
                Bbase + ((f * 16 + cl) << 9) + ks * 32 + hi * 8);
        #pragma unroll
        for (int tt = 0; tt < 2; ++tt)
            afr[tt] = *reinterpret_cast<const short8*>(
                (char*)A_lds + (tt * 16 + cl) * 1024 + ((ks * 64 + hi * 16) ^ aswz));
        #pragma unroll
        for (int tt = 0; tt < 2; ++tt)
            #pragma unroll
            for (int f = 0; f < 4; ++f)
                acc[tt][f] = __builtin_amdgcn_mfma_f32_16x16x32_bf16(
                    afr[tt], bfr[f], acc[tt][f], 0, 0, 0);
    }

    // ---- epilogue: inv, tanh, w2-dot -> per-row partials for this col-slice ----
    float sp[2][4];
    #pragma unroll
    for (int tt = 0; tt < 2; ++tt)
        #pragma unroll
        for (int i = 0; i < 4; ++i) sp[tt][i] = 0.f;

    #pragma unroll
    for (int f = 0; f < 4; ++f) {
        int col = w * 64 + f * 16 + cl;
        float wv = W2v[col];
        float bb = b1[col];
        #pragma unroll
        for (int tt = 0; tt < 2; ++tt) {
            #pragma unroll
            for (int i = 0; i < 4; ++i) {
                float iv = inv_s[tt * 16 + hi * 4 + i];
                sp[tt][i] += wv * fast_tanh(acc[tt][f][i] * iv + bb);
            }
        }
    }

    // reduce over the 16 col-lanes; C/D row = hi*4+i within tile tt
    #pragma unroll
    for (int tt = 0; tt < 2; ++tt) {
        #pragma unroll
        for (int i = 0; i < 4; ++i) {
            float v = sp[tt][i];
            v += __shfl_xor(v, 1, 64);
            v += __shfl_xor(v, 2, 64);
            v += __shfl_xor(v, 4, 64);
            v += __shfl_xor(v, 8, 64);
            if (cl == 0) scorebuf[w][tt * 16 + hi * 4 + i] = v;
        }
    }
    __syncthreads();

    // sum the 8 per-wave col-slice partials -> final scores
    if (t < 32) {
        float s = 0.f;
        #pragma unroll
        for (int q = 0; q < 8; ++q) s += scorebuf[q][t];
        scores[row0 + t] = s;
    }
}

// ---- kernel 3: softmax over r + fp32 weighted pooling ----
// 512 blocks (one per (b,n) group) x 512 threads; thread t owns d-column t.
__global__ __launch_bounds__(512) void softmax_pool(
    const float* __restrict__ x, const float* __restrict__ inv_norm,
    const float* __restrict__ scores, float* __restrict__ out) {

    __shared__ float F[RREG];
    __shared__ float wts[RREG];
    const int t = threadIdx.x;
    const int g = blockIdx.x;

    float s = 0.f, e = 0.f;
    if (t < RREG) { s = scores[g * RREG + t]; F[t] = s; }
    __syncthreads();
    for (int off = 128; off > 0; off >>= 1) {
        if (t < off) F[t] = fmaxf(F[t], F[t + off]);
        __syncthreads();
    }
    float mx = F[0];
    __syncthreads();
    if (t < RREG) { e = expf(s - mx); F[t] = e; }
    __syncthreads();
    for (int off = 128; off > 0; off >>= 1) {
        if (t < off) F[t] += F[t + off];
        __syncthreads();
    }
    float denom = F[0];
    if (t < RREG) {
        float al = e / denom;
        out[FBAR_ELEMS + (size_t)g * RREG + t] = al;          // output 1: alphas
        wts[t] = al * inv_norm[(size_t)g * RREG + t];
    }
    __syncthreads();

    // fbar[d=t] = sum_r (alpha_r * inv_r) * x[g,r,t]  (coalesced 2 KB/row)
    float a = 0.f;
    const float* xb = x + (size_t)g * RREG * D + t;
    #pragma unroll 8
    for (int r = 0; r < RREG; ++r) a += wts[r] * xb[(size_t)r * D];
    out[(size_t)g * D + t] = a;                               // output 0: fbar
}

extern "C" void kernel_launch(void* const* d_in, const int* in_sizes, int n_in,
                              void* d_out, int out_size, void* d_ws, size_t ws_size,
                              hipStream_t stream) {
    const float* x  = (const float*)d_in[0];
    const float* W1 = (const float*)d_in[1];
    const float* b1 = (const float*)d_in[2];
    const float* w2 = (const float*)d_in[3];
    // b2 (d_in[4]) shifts all scores uniformly -> softmax-invariant -> unused.
    float* out = (float*)d_out;

    unsigned short* W1bf = (unsigned short*)d_ws;                    // 512 KiB
    float* inv_norm = (float*)((char*)d_ws + 524288);                // 512 KiB
    float* scores   = (float*)((char*)d_ws + 1048576);               // 512 KiB

    conv_w1<<<256, 256, 0, stream>>>(W1, W1bf);
    score_gemm<<<ROWS / 32, 512, 0, stream>>>(x, W1bf, b1, w2, inv_norm, scores);
    softmax_pool<<<NGROUP, 512, 0, stream>>>(x, inv_norm, scores, out);
}

// Round 8
// 242.098 us; speedup vs baseline: 1.2174x; 1.2174x over previous
//
#include <hip/hip_runtime.h>
#include <hip/hip_bf16.h>

typedef short short8 __attribute__((ext_vector_type(8)));
typedef float floatx4 __attribute__((ext_vector_type(4)));

#define NGROUP 512
#define RREG 256
#define D 512
#define ROWS 131072
#define FBAR_ELEMS (NGROUP * D)   // 262144

__device__ __forceinline__ unsigned short f2bf(float f) {
    unsigned int u = __float_as_uint(f);
    unsigned int r = (u + 0x7fffu + ((u >> 16) & 1u)) >> 16;
    return (unsigned short)r;
}
__device__ __forceinline__ float fast_tanh(float x) {
    float cx = fminf(fmaxf(x, -9.5f), 9.5f);
    float e  = __builtin_amdgcn_exp2f(cx * 2.8853900817779268f);  // e^{2cx}
    return (e - 1.f) * __builtin_amdgcn_rcpf(e + 1.f);
}

// ---- kernel 1: W1 fp32 -> bf16, plain row-major [outcol][k] ----
__global__ __launch_bounds__(256) void conv_w1(const float* __restrict__ W1,
                                               unsigned short* __restrict__ W1bf) {
    int i = (blockIdx.x * 256 + threadIdx.x) * 4;
    float4 v = *reinterpret_cast<const float4*>(W1 + i);
    ushort4 o;
    o.x = f2bf(v.x); o.y = f2bf(v.y); o.z = f2bf(v.z); o.w = f2bf(v.w);
    *reinterpret_cast<ushort4*>(W1bf + i) = o;
}

// ---- kernel 2: score GEMM (R5 structure) ----
// 2048 blocks x 512 threads (8 waves). Block = 64 rows of x, 64 KiB LDS
// -> 2 blocks/CU. Wave w owns the 64-row x 64-col slice cols
// [w*64,w*64+64): A from swizzled LDS (reused x4), B from global
// (L2-resident W1bf) straight to registers.
// KEY CHANGE vs R5/R7: __launch_bounds__(512,1) lifts the default 64-VGPR
// cap (hipcc assumes 1024-thread blocks without it; R5=64, R7=48 VGPRs ->
// no load window -> 200-cyc L2 latency exposed per ks step). With cap 256
// the compiler lands ~128 (R4 evidence), keeping 4 waves/SIMD while
// holding a multi-ks B/A prefetch window. K-loop fully unrolled so the
// scheduler can slide that window across the whole loop.
__global__ __launch_bounds__(512, 1) void score_gemm(
    const float* __restrict__ x, const unsigned short* __restrict__ W1bf,
    const float* __restrict__ b1, const float* __restrict__ W2v,
    float* __restrict__ inv_norm, float* __restrict__ scores) {

    __shared__ unsigned short A_lds[64 * 512];   // 64 KiB, swizzled
    __shared__ float inv_s[64];
    __shared__ float scorebuf[8][64];            // 2 KiB

    const int t = threadIdx.x;
    const int lane = t & 63;
    const int w = t >> 6;          // wave 0..7
    const int cl = lane & 15;
    const int hi = lane >> 4;
    const size_t row0 = (size_t)blockIdx.x * 64;

    // ---- stage A: wave w owns rows w*8 .. w*8+7; loads issued first ----
    {
        const float* xw = x + (row0 + w * 8) * (size_t)D + lane * 8;
        float4 v[8][2];
        #pragma unroll
        for (int i = 0; i < 8; ++i) {           // 16 independent loads in flight
            v[i][0] = *reinterpret_cast<const float4*>(xw + (size_t)i * D);
            v[i][1] = *reinterpret_cast<const float4*>(xw + (size_t)i * D + 4);
        }
        #pragma unroll
        for (int i = 0; i < 8; ++i) {
            int r = w * 8 + i;
            float4 p = v[i][0], q = v[i][1];
            float ss = p.x*p.x + p.y*p.y + p.z*p.z + p.w*p.w
                     + q.x*q.x + q.y*q.y + q.z*q.z + q.w*q.w;
            #pragma unroll
            for (int m = 1; m < 64; m <<= 1) ss += __shfl_xor(ss, m, 64);
            float inv = 1.0f / fmaxf(sqrtf(ss), 1e-12f);
            if (lane == 0) { inv_s[r] = inv; inv_norm[row0 + r] = inv; }
            short8 pk;
            pk[0] = (short)f2bf(p.x); pk[1] = (short)f2bf(p.y);
            pk[2] = (short)f2bf(p.z); pk[3] = (short)f2bf(p.w);
            pk[4] = (short)f2bf(q.x); pk[5] = (short)f2bf(q.y);
            pk[6] = (short)f2bf(q.z); pk[7] = (short)f2bf(q.w);
            // 16B slot per lane, XOR-swizzled by row (matches A-frag reads:
            // slot bits[6:4] = (4ks+hi) ^ (cl&7) -> conflict-free)
            *reinterpret_cast<short8*>(
                (char*)A_lds + r * 1024 + ((lane * 16) ^ ((r & 7) << 4))) = pk;
        }
    }
    __syncthreads();

    // ---- GEMM: K=512 in 16 steps of 32, fully unrolled ----
    floatx4 acc[4][4];
    #pragma unroll
    for (int tt = 0; tt < 4; ++tt)
        #pragma unroll
        for (int f = 0; f < 4; ++f) acc[tt][f] = floatx4{0, 0, 0, 0};

    const unsigned short* Bbase = W1bf + ((size_t)(w * 64) << 9);  // cols w*64..
    const int aswz = (cl & 7) << 4;

    #pragma unroll
    for (int ks = 0; ks < 16; ++ks) {
        short8 bfr[4], afr[4];
        #pragma unroll
        for (int f = 0; f < 4; ++f)
            bfr[f] = *reinterpret_cast<const short8*>(
                Bbase + ((f * 16 + cl) << 9) + ks * 32 + hi * 8);
        #pragma unroll
        for (int tt = 0; tt < 4; ++tt)
            afr[tt] = *reinterpret_cast<const short8*>(
                (char*)A_lds + (tt * 16 + cl) * 1024 + ((ks * 64 + hi * 16) ^ aswz));
        #pragma unroll
        for (int tt = 0; tt < 4; ++tt)
            #pragma unroll
            for (int f = 0; f < 4; ++f)
                acc[tt][f] = __builtin_amdgcn_mfma_f32_16x16x32_bf16(
                    afr[tt], bfr[f], acc[tt][f], 0, 0, 0);
    }

    // ---- epilogue: inv, tanh, w2-dot -> per-row partials for this col-slice ----
    float sp[4][4];
    #pragma unroll
    for (int tt = 0; tt < 4; ++tt)
        #pragma unroll
        for (int i = 0; i < 4; ++i) sp[tt][i] = 0.f;

    #pragma unroll
    for (int f = 0; f < 4; ++f) {
        int col = w * 64 + f * 16 + cl;
        float wv = W2v[col];
        float bb = b1[col];
        #pragma unroll
        for (int tt = 0; tt < 4; ++tt) {
            #pragma unroll
            for (int i = 0; i < 4; ++i) {
                float iv = inv_s[tt * 16 + hi * 4 + i];
                sp[tt][i] += wv * fast_tanh(acc[tt][f][i] * iv + bb);
            }
        }
    }

    // reduce over the 16 col-lanes; C/D row = hi*4+i within tile tt
    #pragma unroll
    for (int tt = 0; tt < 4; ++tt) {
        #pragma unroll
        for (int i = 0; i < 4; ++i) {
            float v = sp[tt][i];
            v += __shfl_xor(v, 1, 64);
            v += __shfl_xor(v, 2, 64);
            v += __shfl_xor(v, 4, 64);
            v += __shfl_xor(v, 8, 64);
            if (cl == 0) scorebuf[w][tt * 16 + hi * 4 + i] = v;
        }
    }
    __syncthreads();

    // sum the 8 per-wave col-slice partials -> final scores
    if (t < 64) {
        float s = 0.f;
        #pragma unroll
        for (int q = 0; q < 8; ++q) s += scorebuf[q][t];
        scores[row0 + t] = s;
    }
}

// ---- kernel 3: softmax over r + fp32 weighted pooling ----
// 512 blocks (one per (b,n) group) x 512 threads; thread t owns d-column t.
__global__ __launch_bounds__(512) void softmax_pool(
    const float* __restrict__ x, const float* __restrict__ inv_norm,
    const float* __restrict__ scores, float* __restrict__ out) {

    __shared__ float F[RREG];
    __shared__ float wts[RREG];
    const int t = threadIdx.x;
    const int g = blockIdx.x;

    float s = 0.f, e = 0.f;
    if (t < RREG) { s = scores[g * RREG + t]; F[t] = s; }
    __syncthreads();
    for (int off = 128; off > 0; off >>= 1) {
        if (t < off) F[t] = fmaxf(F[t], F[t + off]);
        __syncthreads();
    }
    float mx = F[0];
    __syncthreads();
    if (t < RREG) { e = expf(s - mx); F[t] = e; }
    __syncthreads();
    for (int off = 128; off > 0; off >>= 1) {
        if (t < off) F[t] += F[t + off];
        __syncthreads();
    }
    float denom = F[0];
    if (t < RREG) {
        float al = e / denom;
        out[FBAR_ELEMS + (size_t)g * RREG + t] = al;          // output 1: alphas
        wts[t] = al * inv_norm[(size_t)g * RREG + t];
    }
    __syncthreads();

    // fbar[d=t] = sum_r (alpha_r * inv_r) * x[g,r,t]  (coalesced 2 KB/row)
    float a = 0.f;
    const float* xb = x + (size_t)g * RREG * D + t;
    #pragma unroll 16
    for (int r = 0; r < RREG; ++r) a += wts[r] * xb[(size_t)r * D];
    out[(size_t)g * D + t] = a;                               // output 0: fbar
}

extern "C" void kernel_launch(void* const* d_in, const int* in_sizes, int n_in,
                              void* d_out, int out_size, void* d_ws, size_t ws_size,
                              hipStream_t stream) {
    const float* x  = (const float*)d_in[0];
    const float* W1 = (const float*)d_in[1];
    const float* b1 = (const float*)d_in[2];
    const float* w2 = (const float*)d_in[3];
    // b2 (d_in[4]) shifts all scores uniformly -> softmax-invariant -> unused.
    float* out = (float*)d_out;

    unsigned short* W1bf = (unsigned short*)d_ws;                    // 512 KiB
    float* inv_norm = (float*)((char*)d_ws + 524288);                // 512 KiB
    float* scores   = (float*)((char*)d_ws + 1048576);               // 512 KiB

    conv_w1<<<256, 256, 0, stream>>>(W1, W1bf);
    score_gemm<<<ROWS / 64, 512, 0, stream>>>(x, W1bf, b1, w2, inv_norm, scores);
    softmax_pool<<<NGROUP, 512, 0, stream>>>(x, inv_norm, scores, out);
}

// Round 9
// 239.855 us; speedup vs baseline: 1.2288x; 1.0094x over previous
//
#include <hip/hip_runtime.h>
#include <hip/hip_bf16.h>

typedef short short8 __attribute__((ext_vector_type(8)));
typedef float floatx4 __attribute__((ext_vector_type(4)));

#define NGROUP 512
#define RREG 256
#define D 512
#define ROWS 131072
#define FBAR_ELEMS (NGROUP * D)   // 262144

__device__ __forceinline__ unsigned short f2bf(float f) {
    unsigned int u = __float_as_uint(f);
    unsigned int r = (u + 0x7fffu + ((u >> 16) & 1u)) >> 16;
    return (unsigned short)r;
}
__device__ __forceinline__ float fast_tanh(float x) {
    float cx = fminf(fmaxf(x, -9.5f), 9.5f);
    float e  = __builtin_amdgcn_exp2f(cx * 2.8853900817779268f);  // e^{2cx}
    return (e - 1.f) * __builtin_amdgcn_rcpf(e + 1.f);
}

// ---- kernel 1: W1 fp32 -> bf16, K-CHUNKED PRE-SWIZZLED layout ----
// W1c = 16 chunks of 32 KiB. Chunk kc holds k in [kc*32, kc*32+32) for all
// 512 cols: element (col, kc*32+kl) lives at chunk byte
//   col*64 + ((kl*2) ^ ((col&3)<<4)).
// Stored linearly so global_load_lds (linear dest) reproduces the image;
// the XOR spreads the B-frag read (16 rows x 4 k-slots) across all banks.
__global__ __launch_bounds__(256) void conv_w1(const float* __restrict__ W1,
                                               unsigned short* __restrict__ W1c) {
    int tid = blockIdx.x * 256 + threadIdx.x;   // 0..65535
    int P = tid * 8;                            // byte offset in 512 KiB image
    int kc = P >> 15;
    int L = P & 32767;
    int col = L >> 6;
    int q = L & 63;
    int kl = (q ^ ((col & 3) << 4)) >> 1;       // multiple of 4
    const float* src = W1 + col * 512 + kc * 32 + kl;
    float4 v = *reinterpret_cast<const float4*>(src);
    ushort4 o;
    o.x = f2bf(v.x); o.y = f2bf(v.y); o.z = f2bf(v.z); o.w = f2bf(v.w);
    *reinterpret_cast<ushort4*>((char*)W1c + P) = o;
}

// ---- kernel 2: score GEMM, B via global_load_lds double-buffer ----
// 2048 blocks x 512 threads (8 waves). Block = 64 rows of x, full N=512.
// A: 64 KiB swizzled LDS, staged once with normalize (R5-proven layout).
// B: K-chunked (32 k) 32 KiB chunks DMA'd from pre-swizzled W1c,
// double-buffered; per K-step: issue DMA(s+1), ds_read frags(s), 16 MFMA,
// barrier. The DMA window lives in the vmcnt queue, not VGPRs (R6-R8
// lesson: the compiler never holds a register prefetch window).
__global__ __launch_bounds__(512) void score_gemm(
    const float* __restrict__ x, const unsigned short* __restrict__ W1c,
    const float* __restrict__ b1, const float* __restrict__ W2v,
    float* __restrict__ inv_norm, float* __restrict__ scores) {

    __shared__ unsigned short A_lds[64 * 512];     // 64 KiB, swizzled
    __shared__ unsigned short B_lds[2][16384];     // 2 x 32 KiB (one K-chunk)
    __shared__ float inv_s[64];
    __shared__ float scorebuf[8][64];              // 2 KiB

    const int t = threadIdx.x;
    const int lane = t & 63;
    const int w = t >> 6;          // wave 0..7
    const int cl = lane & 15;
    const int hi = lane >> 4;
    const size_t row0 = (size_t)blockIdx.x * 64;

    // stage one 32 KiB B chunk (kc) into buffer buf; linear dest, src pre-swizzled
    auto stageB = [&](int buf, int kc) {
        const char* gb = (const char*)W1c + kc * 32768 + w * 4096 + lane * 16;
        char* lb = (char*)B_lds[buf] + w * 4096;
        #pragma unroll
        for (int i = 0; i < 4; ++i) {
            __builtin_amdgcn_global_load_lds(
                (const __attribute__((address_space(1))) void*)(gb + i * 1024),
                (__attribute__((address_space(3))) void*)(lb + i * 1024),
                16, 0, 0);
        }
    };

    stageB(0, 0);   // in flight during A staging

    // ---- stage A: wave w owns rows w*8..w*8+7; loads issued first ----
    {
        const float* xw = x + (row0 + w * 8) * (size_t)D + lane * 8;
        float4 v[8][2];
        #pragma unroll
        for (int i = 0; i < 8; ++i) {           // 16 independent loads in flight
            v[i][0] = *reinterpret_cast<const float4*>(xw + (size_t)i * D);
            v[i][1] = *reinterpret_cast<const float4*>(xw + (size_t)i * D + 4);
        }
        #pragma unroll
        for (int i = 0; i < 8; ++i) {
            int r = w * 8 + i;
            float4 p = v[i][0], q = v[i][1];
            float ss = p.x*p.x + p.y*p.y + p.z*p.z + p.w*p.w
                     + q.x*q.x + q.y*q.y + q.z*q.z + q.w*q.w;
            #pragma unroll
            for (int m = 1; m < 64; m <<= 1) ss += __shfl_xor(ss, m, 64);
            float inv = 1.0f / fmaxf(sqrtf(ss), 1e-12f);
            if (lane == 0) { inv_s[r] = inv; inv_norm[row0 + r] = inv; }
            short8 pk;
            pk[0] = (short)f2bf(p.x); pk[1] = (short)f2bf(p.y);
            pk[2] = (short)f2bf(p.z); pk[3] = (short)f2bf(p.w);
            pk[4] = (short)f2bf(q.x); pk[5] = (short)f2bf(q.y);
            pk[6] = (short)f2bf(q.z); pk[7] = (short)f2bf(q.w);
            *reinterpret_cast<short8*>(
                (char*)A_lds + r * 1024 + ((lane * 16) ^ ((r & 7) << 4))) = pk;
        }
    }
    __syncthreads();   // A visible; stageB(0) drained by the barrier's vmcnt wait

    // ---- GEMM: K=512 in 16 chunk-steps of 32 ----
    floatx4 acc[4][4];
    #pragma unroll
    for (int tt = 0; tt < 4; ++tt)
        #pragma unroll
        for (int f = 0; f < 4; ++f) acc[tt][f] = floatx4{0, 0, 0, 0};

    const int aswz = (cl & 7) << 4;

    #pragma unroll 2
    for (int s = 0; s < 16; ++s) {
        if (s < 15) stageB((s + 1) & 1, s + 1);   // DMA next chunk (other buffer)

        const char* Bb = (const char*)B_lds[s & 1];
        short8 bfr[4], afr[4];
        #pragma unroll
        for (int f = 0; f < 4; ++f) {
            int c = w * 64 + f * 16 + cl;
            bfr[f] = *reinterpret_cast<const short8*>(
                Bb + c * 64 + ((hi * 16) ^ ((c & 3) << 4)));
        }
        #pragma unroll
        for (int tt = 0; tt < 4; ++tt)
            afr[tt] = *reinterpret_cast<const short8*>(
                (char*)A_lds + (tt * 16 + cl) * 1024 + ((s * 64 + hi * 16) ^ aswz));

        #pragma unroll
        for (int tt = 0; tt < 4; ++tt)
            #pragma unroll
            for (int f = 0; f < 4; ++f)
                acc[tt][f] = __builtin_amdgcn_mfma_f32_16x16x32_bf16(
                    afr[tt], bfr[f], acc[tt][f], 0, 0, 0);

        __syncthreads();   // drains DMA(s+1); all waves done reading buf[s&1]
    }

    // ---- epilogue: inv, tanh, w2-dot -> per-row partials for this col-slice ----
    float sp[4][4];
    #pragma unroll
    for (int tt = 0; tt < 4; ++tt)
        #pragma unroll
        for (int i = 0; i < 4; ++i) sp[tt][i] = 0.f;

    #pragma unroll
    for (int f = 0; f < 4; ++f) {
        int col = w * 64 + f * 16 + cl;
        float wv = W2v[col];
        float bb = b1[col];
        #pragma unroll
        for (int tt = 0; tt < 4; ++tt) {
            #pragma unroll
            for (int i = 0; i < 4; ++i) {
                float iv = inv_s[tt * 16 + hi * 4 + i];
                sp[tt][i] += wv * fast_tanh(acc[tt][f][i] * iv + bb);
            }
        }
    }

    // reduce over the 16 col-lanes; C/D row = hi*4+i within tile tt
    #pragma unroll
    for (int tt = 0; tt < 4; ++tt) {
        #pragma unroll
        for (int i = 0; i < 4; ++i) {
            float v = sp[tt][i];
            v += __shfl_xor(v, 1, 64);
            v += __shfl_xor(v, 2, 64);
            v += __shfl_xor(v, 4, 64);
            v += __shfl_xor(v, 8, 64);
            if (cl == 0) scorebuf[w][tt * 16 + hi * 4 + i] = v;
        }
    }
    __syncthreads();

    // sum the 8 per-wave col-slice partials -> final scores
    if (t < 64) {
        float s = 0.f;
        #pragma unroll
        for (int q = 0; q < 8; ++q) s += scorebuf[q][t];
        scores[row0 + t] = s;
    }
}

// ---- kernel 3: softmax over r + fp32 weighted pooling ----
__global__ __launch_bounds__(512) void softmax_pool(
    const float* __restrict__ x, const float* __restrict__ inv_norm,
    const float* __restrict__ scores, float* __restrict__ out) {

    __shared__ float F[RREG];
    __shared__ float wts[RREG];
    const int t = threadIdx.x;
    const int g = blockIdx.x;

    float s = 0.f, e = 0.f;
    if (t < RREG) { s = scores[g * RREG + t]; F[t] = s; }
    __syncthreads();
    for (int off = 128; off > 0; off >>= 1) {
        if (t < off) F[t] = fmaxf(F[t], F[t + off]);
        __syncthreads();
    }
    float mx = F[0];
    __syncthreads();
    if (t < RREG) { e = expf(s - mx); F[t] = e; }
    __syncthreads();
    for (int off = 128; off > 0; off >>= 1) {
        if (t < off) F[t] += F[t + off];
        __syncthreads();
    }
    float denom = F[0];
    if (t < RREG) {
        float al = e / denom;
        out[FBAR_ELEMS + (size_t)g * RREG + t] = al;          // output 1: alphas
        wts[t] = al * inv_norm[(size_t)g * RREG + t];
    }
    __syncthreads();

    // fbar[d=t] = sum_r (alpha_r * inv_r) * x[g,r,t]  (coalesced 2 KB/row)
    float a = 0.f;
    const float* xb = x + (size_t)g * RREG * D + t;
    #pragma unroll 16
    for (int r = 0; r < RREG; ++r) a += wts[r] * xb[(size_t)r * D];
    out[(size_t)g * D + t] = a;                               // output 0: fbar
}

extern "C" void kernel_launch(void* const* d_in, const int* in_sizes, int n_in,
                              void* d_out, int out_size, void* d_ws, size_t ws_size,
                              hipStream_t stream) {
    const float* x  = (const float*)d_in[0];
    const float* W1 = (const float*)d_in[1];
    const float* b1 = (const float*)d_in[2];
    const float* w2 = (const float*)d_in[3];
    // b2 (d_in[4]) shifts all scores uniformly -> softmax-invariant -> unused.
    float* out = (float*)d_out;

    unsigned short* W1c = (unsigned short*)d_ws;                     // 512 KiB
    float* inv_norm = (float*)((char*)d_ws + 524288);                // 512 KiB
    float* scores   = (float*)((char*)d_ws + 1048576);               // 512 KiB

    conv_w1<<<256, 256, 0, stream>>>(W1, W1c);
    score_gemm<<<ROWS / 64, 512, 0, stream>>>(x, W1c, b1, w2, inv_norm, scores);
    softmax_pool<<<NGROUP, 512, 0, stream>>>(x, inv_norm, scores, out);
}

// Round 10
// 185.343 us; speedup vs baseline: 1.5902x; 1.2941x over previous
//
#include <hip/hip_runtime.h>
#include <hip/hip_bf16.h>

typedef short short8 __attribute__((ext_vector_type(8)));
typedef float floatx4 __attribute__((ext_vector_type(4)));

#define NGROUP 512
#define RREG 256
#define D 512
#define ROWS 131072
#define FBAR_ELEMS (NGROUP * D)   // 262144

__device__ __forceinline__ unsigned short f2bf(float f) {
    unsigned int u = __float_as_uint(f);
    unsigned int r = (u + 0x7fffu + ((u >> 16) & 1u)) >> 16;
    return (unsigned short)r;
}
__device__ __forceinline__ float fast_tanh(float x) {
    float cx = fminf(fmaxf(x, -9.5f), 9.5f);
    float e  = __builtin_amdgcn_exp2f(cx * 2.8853900817779268f);  // e^{2cx}
    return (e - 1.f) * __builtin_amdgcn_rcpf(e + 1.f);
}

// ---- kernel 1: W1 fp32 -> bf16, K-CHUNKED PRE-SWIZZLED layout (as R9) ----
// W1c = 16 chunks of 32 KiB. Chunk kc holds k in [kc*32,kc*32+32) for all 512
// cols: element (col, kc*32+kl) at chunk byte col*64 + ((kl*2) ^ ((col&3)<<4)).
__global__ __launch_bounds__(256) void conv_w1(const float* __restrict__ W1,
                                               unsigned short* __restrict__ W1c) {
    int tid = blockIdx.x * 256 + threadIdx.x;   // 0..65535
    int P = tid * 8;                            // byte offset in 512 KiB image
    int kc = P >> 15;
    int L = P & 32767;
    int col = L >> 6;
    int q = L & 63;
    int kl = (q ^ ((col & 3) << 4)) >> 1;       // multiple of 4
    const float* src = W1 + col * 512 + kc * 32 + kl;
    float4 v = *reinterpret_cast<const float4*>(src);
    ushort4 o;
    o.x = f2bf(v.x); o.y = f2bf(v.y); o.z = f2bf(v.z); o.w = f2bf(v.w);
    *reinterpret_cast<ushort4*>((char*)W1c + P) = o;
}

// ---- kernel 2: score GEMM, wave-private B DMA + counted vmcnt ----
// 2048 blocks x 512 threads (8 waves). Block = 64 rows x full N=512.
// A: 64 KiB swizzled LDS, staged once with normalize (one __syncthreads).
// B: each wave DMAs ONLY its own 64-col slice (4 KB per 32-k chunk) into its
// own triple-buffered LDS region -> the 16-step GEMM loop has NO barriers.
// Counted s_waitcnt vmcnt(8) keeps 2 chunks in flight (T3/T4 pattern);
// vmcnt never drains to 0 in steady state (R9 lesson: __syncthreads'
// vmcnt(0) drain + 8-wave convoy serialized every step).
// LDS = 65536 (A) + 3*8*4096 (B) = 163840 B exactly (512B-granular, fits).
__global__ __launch_bounds__(512) void score_gemm(
    const float* __restrict__ x, const unsigned short* __restrict__ W1c,
    const float* __restrict__ b1, const float* __restrict__ W2v,
    float* __restrict__ inv_norm, float* __restrict__ scores) {

    __shared__ unsigned short A_lds[32768];   // 64 KiB (64 rows x 1 KiB, swizzled)
    __shared__ char B_lds[3][8][4096];        // 96 KiB: [buf][wave][slice]

    const int t = threadIdx.x;
    const int lane = t & 63;
    const int w = t >> 6;          // wave 0..7
    const int cl = lane & 15;
    const int hi = lane >> 4;
    const size_t row0 = (size_t)blockIdx.x * 64;

    // wave-private stage: chunk kc's 64-col slice for wave w -> B_lds[buf][w]
    auto stageB = [&](int buf, int kc) {
        const char* gb = (const char*)W1c + kc * 32768 + w * 4096 + lane * 16;
        char* lb = &B_lds[buf][w][0];
        #pragma unroll
        for (int i = 0; i < 4; ++i) {
            __builtin_amdgcn_global_load_lds(
                (const __attribute__((address_space(1))) void*)(gb + i * 1024),
                (__attribute__((address_space(3))) void*)(lb + i * 1024),
                16, 0, 0);
        }
    };

    stageB(0, 0);   // chunks 0,1 in flight during A staging
    stageB(1, 1);

    // ---- stage A: wave w owns rows w*8..w*8+7; loads issued first ----
    {
        const float* xw = x + (row0 + w * 8) * (size_t)D + lane * 8;
        float4 v[8][2];
        #pragma unroll
        for (int i = 0; i < 8; ++i) {           // 16 independent loads in flight
            v[i][0] = *reinterpret_cast<const float4*>(xw + (size_t)i * D);
            v[i][1] = *reinterpret_cast<const float4*>(xw + (size_t)i * D + 4);
        }
        #pragma unroll
        for (int i = 0; i < 8; ++i) {
            int r = w * 8 + i;
            float4 p = v[i][0], q = v[i][1];
            float ss = p.x*p.x + p.y*p.y + p.z*p.z + p.w*p.w
                     + q.x*q.x + q.y*q.y + q.z*q.z + q.w*q.w;
            #pragma unroll
            for (int m = 1; m < 64; m <<= 1) ss += __shfl_xor(ss, m, 64);
            float inv = 1.0f / fmaxf(sqrtf(ss), 1e-12f);
            if (lane == 0) inv_norm[row0 + r] = inv;
            short8 pk;
            pk[0] = (short)f2bf(p.x); pk[1] = (short)f2bf(p.y);
            pk[2] = (short)f2bf(p.z); pk[3] = (short)f2bf(p.w);
            pk[4] = (short)f2bf(q.x); pk[5] = (short)f2bf(q.y);
            pk[6] = (short)f2bf(q.z); pk[7] = (short)f2bf(q.w);
            *reinterpret_cast<short8*>(
                (char*)A_lds + r * 1024 + ((lane * 16) ^ ((r & 7) << 4))) = pk;
        }
    }
    __syncthreads();   // A visible to all waves (also drains chunks 0,1)

    // ---- GEMM: K=512 in 16 chunk-steps of 32; barrier-free, counted waits ----
    floatx4 acc[4][4];
    #pragma unroll
    for (int tt = 0; tt < 4; ++tt)
        #pragma unroll
        for (int f = 0; f < 4; ++f) acc[tt][f] = floatx4{0, 0, 0, 0};

    const int aswz = (cl & 7) << 4;
    const int bofs = (hi * 16) ^ ((cl & 3) << 4);

    #pragma unroll
    for (int s = 0; s < 16; ++s) {
        if (s <= 13) {
            stageB((s + 2) % 3, s + 2);    // distance-2 prefetch (4 ops)
            // chunk s done; chunks s+1, s+2 (8 ops) stay in flight
            asm volatile("s_waitcnt vmcnt(8)" ::: "memory");
        } else if (s == 14) {
            asm volatile("s_waitcnt vmcnt(4)" ::: "memory");   // chunk 14 done
        } else {
            asm volatile("s_waitcnt vmcnt(0)" ::: "memory");   // chunk 15 done
        }

        const char* Bb = &B_lds[s % 3][w][0];
        short8 bfr[4], afr[4];
        #pragma unroll
        for (int f = 0; f < 4; ++f)
            bfr[f] = *reinterpret_cast<const short8*>(Bb + (f * 16 + cl) * 64 + bofs);
        #pragma unroll
        for (int tt = 0; tt < 4; ++tt)
            afr[tt] = *reinterpret_cast<const short8*>(
                (char*)A_lds + (tt * 16 + cl) * 1024 + ((s * 64 + hi * 16) ^ aswz));

        #pragma unroll
        for (int tt = 0; tt < 4; ++tt)
            #pragma unroll
            for (int f = 0; f < 4; ++f)
                acc[tt][f] = __builtin_amdgcn_mfma_f32_16x16x32_bf16(
                    afr[tt], bfr[f], acc[tt][f], 0, 0, 0);
    }

    // ---- epilogue: inv (re-read from global), tanh, w2-dot ----
    float sp[4][4];
    #pragma unroll
    for (int tt = 0; tt < 4; ++tt)
        #pragma unroll
        for (int i = 0; i < 4; ++i) sp[tt][i] = 0.f;

    float4 iv4[4];
    #pragma unroll
    for (int tt = 0; tt < 4; ++tt)
        iv4[tt] = *reinterpret_cast<const float4*>(inv_norm + row0 + tt * 16 + hi * 4);

    #pragma unroll
    for (int f = 0; f < 4; ++f) {
        int col = w * 64 + f * 16 + cl;
        float wv = W2v[col];
        float bb = b1[col];
        #pragma unroll
        for (int tt = 0; tt < 4; ++tt) {
            sp[tt][0] += wv * fast_tanh(acc[tt][f][0] * iv4[tt].x + bb);
            sp[tt][1] += wv * fast_tanh(acc[tt][f][1] * iv4[tt].y + bb);
            sp[tt][2] += wv * fast_tanh(acc[tt][f][2] * iv4[tt].z + bb);
            sp[tt][3] += wv * fast_tanh(acc[tt][f][3] * iv4[tt].w + bb);
        }
    }

    // reduce over the 16 col-lanes; C/D row = hi*4+i within tile tt
    float red[4][4];
    #pragma unroll
    for (int tt = 0; tt < 4; ++tt) {
        #pragma unroll
        for (int i = 0; i < 4; ++i) {
            float v = sp[tt][i];
            v += __shfl_xor(v, 1, 64);
            v += __shfl_xor(v, 2, 64);
            v += __shfl_xor(v, 4, 64);
            v += __shfl_xor(v, 8, 64);
            red[tt][i] = v;
        }
    }

    __syncthreads();   // all waves done with A_lds -> reuse as scorebuf
    float* scorebuf = (float*)A_lds;   // [8][64]
    if (cl == 0) {
        #pragma unroll
        for (int tt = 0; tt < 4; ++tt)
            #pragma unroll
            for (int i = 0; i < 4; ++i)
                scorebuf[w * 64 + tt * 16 + hi * 4 + i] = red[tt][i];
    }
    __syncthreads();

    if (t < 64) {
        float s = 0.f;
        #pragma unroll
        for (int q = 0; q < 8; ++q) s += scorebuf[q * 64 + t];
        scores[row0 + t] = s;
    }
}

// ---- kernel 3: softmax over r + fp32 weighted pooling ----
__global__ __launch_bounds__(512) void softmax_pool(
    const float* __restrict__ x, const float* __restrict__ inv_norm,
    const float* __restrict__ scores, float* __restrict__ out) {

    __shared__ float F[RREG];
    __shared__ float wts[RREG];
    const int t = threadIdx.x;
    const int g = blockIdx.x;

    float s = 0.f, e = 0.f;
    if (t < RREG) { s = scores[g * RREG + t]; F[t] = s; }
    __syncthreads();
    for (int off = 128; off > 0; off >>= 1) {
        if (t < off) F[t] = fmaxf(F[t], F[t + off]);
        __syncthreads();
    }
    float mx = F[0];
    __syncthreads();
    if (t < RREG) { e = expf(s - mx); F[t] = e; }
    __syncthreads();
    for (int off = 128; off > 0; off >>= 1) {
        if (t < off) F[t] += F[t + off];
        __syncthreads();
    }
    float denom = F[0];
    if (t < RREG) {
        float al = e / denom;
        out[FBAR_ELEMS + (size_t)g * RREG + t] = al;          // output 1: alphas
        wts[t] = al * inv_norm[(size_t)g * RREG + t];
    }
    __syncthreads();

    // fbar[d=t] = sum_r (alpha_r * inv_r) * x[g,r,t]  (coalesced 2 KB/row)
    float a = 0.f;
    const float* xb = x + (size_t)g * RREG * D + t;
    #pragma unroll 16
    for (int r = 0; r < RREG; ++r) a += wts[r] * xb[(size_t)r * D];
    out[(size_t)g * D + t] = a;                               // output 0: fbar
}

extern "C" void kernel_launch(void* const* d_in, const int* in_sizes, int n_in,
                              void* d_out, int out_size, void* d_ws, size_t ws_size,
                              hipStream_t stream) {
    const float* x  = (const float*)d_in[0];
    const float* W1 = (const float*)d_in[1];
    const float* b1 = (const float*)d_in[2];
    const float* w2 = (const float*)d_in[3];
    // b2 (d_in[4]) shifts all scores uniformly -> softmax-invariant -> unused.
    float* out = (float*)d_out;

    unsigned short* W1c = (unsigned short*)d_ws;                     // 512 KiB
    float* inv_norm = (float*)((char*)d_ws + 524288);                // 512 KiB
    float* scores   = (float*)((char*)d_ws + 1048576);               // 512 KiB

    conv_w1<<<256, 256, 0, stream>>>(W1, W1c);
    score_gemm<<<ROWS / 64, 512, 0, stream>>>(x, W1c, b1, w2, inv_norm, scores);
    softmax_pool<<<NGROUP, 512, 0, stream>>>(x, inv_norm, scores, out);
}